// Round 15
// baseline (100.881 us; speedup 1.0000x reference)
//
#include <hip/hip_runtime.h>
#include <hip/hip_bf16.h>
#include <cstdint>

#define DT_F    0.01f
#define NB      16      // batch
#define T_SEQ   2048    // sequence
#define DD      1024    // d_in
#define NS      128     // n_state
#define CHUNK   64      // rows per chunk / scan length
#define NCH     32      // chunks per batch

using f32x4  = __attribute__((ext_vector_type(4))) float;
using bf16x8 = __attribute__((ext_vector_type(8))) short;
using fl4    = __attribute__((ext_vector_type(4))) float;

#define AS1(p) ((const __attribute__((address_space(1))) void*)(p))
#define AS3(p) ((__attribute__((address_space(3))) void*)(p))

__device__ __forceinline__ unsigned short f2bf(float f) {
  union { float f; unsigned u; } v; v.f = f;
  unsigned r = v.u + 0x7fffu + ((v.u >> 16) & 1u);   // RNE
  return (unsigned short)(r >> 16);
}
__device__ __forceinline__ float bf2f(unsigned short s) {
  union { unsigned u; float f; } v; v.u = ((unsigned)s) << 16;
  return v.f;
}
__device__ __forceinline__ unsigned short f2bf_hw(float f) {
  __hip_bfloat16 h = __float2bfloat16(f);
  return __builtin_bit_cast(unsigned short, h);
}

// a_disc and the B_disc row-scale c = sqrt(dt)/denom, from raw A (per n)
__device__ __forceinline__ void adisc_full(float Arn, float Ain,
                                           float& ar, float& ai,
                                           float& cr, float& ci) {
  const float dr = 1.f - 0.5f * DT_F * Arn;
  const float di = -0.5f * DT_F * Ain;
  const float inv = 1.f / (dr * dr + di * di);
  const float nr = 1.f + 0.5f * DT_F * Arn;
  const float nim = 0.5f * DT_F * Ain;
  ar = (nr * dr + nim * di) * inv;        // Re(a_disc)
  ai = (nim * dr - nr * di) * inv;        // Im(a_disc)
  const float s = sqrtf(DT_F);
  cr = s * dr * inv;                       // Re(sqrt(dt)/denom)
  ci = -s * di * inv;                      // Im(sqrt(dt)/denom)
}
__device__ __forceinline__ void adisc(float Arn, float Ain, float& ar, float& ai) {
  float cr, ci; adisc_full(Arn, Ain, ar, ai, cr, ci);
}

// ---------------------------------------------------------------------------
// prep_all: blocks 0..511 convert C->bf16; blocks 512..1023 convert B->bf16.
// ---------------------------------------------------------------------------
__global__ void prep_all(const float* __restrict__ B, const float* __restrict__ C,
                         unsigned short* __restrict__ Bb, unsigned short* __restrict__ Cb) {
  const int blk = blockIdx.x;
  const int tid = threadIdx.x;
  if (blk < 512) {
    const int i = blk * 256 + tid;
    Cb[i] = f2bf(C[i]);
  } else {
    const int i = (blk - 512) * 256 + tid;
    Bb[i] = f2bf(B[i]);
  }
}

// ---------------------------------------------------------------------------
// gemm1s (512 threads / 8 waves, R14 form + nt u-loads):
// s_tile[64 x 128] = cvt(u) * Bb^T, BK=64, swizzled As/Bs
// (byte(r,kb) = r*128 + (kb ^ ((r&7)<<4))).
// Epilogue -> swizzled Bt; 128-thread local scan; Re(h)->Hs, finals->F.
// ---------------------------------------------------------------------------
__global__ __launch_bounds__(512, 4) void gemm1s(const float* __restrict__ U,
                                                 const float* __restrict__ Ar,
                                                 const float* __restrict__ Ai,
                                                 const unsigned short* __restrict__ Bb,
                                                 unsigned short* __restrict__ Hs,
                                                 float* __restrict__ F) {
  __shared__ __align__(16) char smem[24576];
  char* As = smem;             // [64] rows x 128 B, swizzled   8 KB
  char* Bs = smem + 8192;      // [128] rows x 128 B, swizzled 16 KB
  char* Bt = smem;             // epilogue: 64 rows x 256 B swizzled

  const int tid  = threadIdx.x;
  const int lane = tid & 63;
  const int wave = tid >> 6;          // 0..7
  const int blk  = blockIdx.x;
  const size_t m0 = (size_t)blk * CHUNK;

  f32x4 acc[4];
  const f32x4 zero = {0.f, 0.f, 0.f, 0.f};
#pragma unroll
  for (int i = 0; i < 4; ++i) acc[i] = zero;

  const int srow = tid >> 3;            // 0..63
  const int scol = (tid & 7) * 8;       // elements 0..56
  const int sb   = srow * 128 + (((tid & 7) * 16) ^ ((srow & 7) << 4));
  const int growl = lane >> 3;          // 0..7
  const int gcolsw = 8 * ((lane & 7) ^ (lane >> 3));   // pre-swizzled source

  for (int k0 = 0; k0 < DD; k0 += 64) {
    __syncthreads();
    // B stage: wave w rows [w*16, +16), 2 glds (8 rows / 1 KB each)
#pragma unroll
    for (int g = 0; g < 2; ++g) {
      const int row = wave * 16 + g * 8;
      const unsigned short* gb = Bb + (size_t)(row + growl) * DD + k0 + gcolsw;
      __builtin_amdgcn_global_load_lds(AS1(gb), AS3(Bs + row * 128), 16, 0, 0);
    }
    // A stage: 64x64 f32 -> bf16, 8 f32/thread (nt stream loads), swizzled store
    {
      const float* ga = U + (m0 + srow) * DD + k0 + scol;
      fl4 v0 = __builtin_nontemporal_load((const fl4*)ga);
      fl4 v1 = __builtin_nontemporal_load((const fl4*)(ga + 4));
      bf16x8 p0;
#pragma unroll
      for (int e = 0; e < 4; ++e) {
        p0[e] = (short)f2bf_hw(v0[e]); p0[4 + e] = (short)f2bf_hw(v1[e]);
      }
      *(bf16x8*)(As + sb) = p0;
    }
    __syncthreads();
#pragma unroll
    for (int ks = 0; ks < 2; ++ks) {
      const int colb = ks * 64 + (lane >> 4) * 16;   // byte within row
      bf16x8 af[4], bfr;
#pragma unroll
      for (int i = 0; i < 4; ++i) {
        const int r = i * 16 + (lane & 15);
        af[i] = *(const bf16x8*)(As + r * 128 + (colb ^ ((r & 7) << 4)));
      }
      {
        const int r = wave * 16 + (lane & 15);
        bfr = *(const bf16x8*)(Bs + r * 128 + (colb ^ ((r & 7) << 4)));
      }
#pragma unroll
      for (int i = 0; i < 4; ++i)
        acc[i] = __builtin_amdgcn_mfma_f32_16x16x32_bf16(af[i], bfr, acc[i], 0, 0, 0);
    }
  }
  __syncthreads();   // MFMA LDS reads done before Bt overwrites As/Bs

  // epilogue: acc -> swizzled Bt. byte(t, n) = t*256 + ((n*2) ^ ((t&7)<<4))
#pragma unroll
  for (int i = 0; i < 4; ++i) {
    const int n = wave * 16 + (lane & 15);
#pragma unroll
    for (int q = 0; q < 4; ++q) {
      const int t = i * 16 + (lane >> 4) * 4 + q;
      *(unsigned short*)(Bt + t * 256 + ((n * 2) ^ ((t & 7) << 4))) = f2bf_hw(acc[i][q]);
    }
  }
  __syncthreads();

  // local scan (threads 0..127): br = cr*s, bi = ci*s; Re(h)->Hs; finals->F
  if (tid < 128) {
    const int n = tid;
    float ar, ai, cr, ci; adisc_full(Ar[n], Ai[n], ar, ai, cr, ci);
    float hr = 0.f, hi = 0.f;
    unsigned short* o = Hs + (size_t)blk * (CHUNK * NS) + n;
#pragma unroll 8
    for (int t = 0; t < CHUNK; ++t) {
      const float s = bf2f(*(const unsigned short*)(Bt + t * 256 + ((n * 2) ^ ((t & 7) << 4))));
      const float br = cr * s;
      const float bi = ci * s;
      const float xr = fmaf(ar, hr, fmaf(-ai, hi, br));
      const float xi = fmaf(ar, hi, fmaf(ai, hr, bi));
      hr = xr; hi = xi;
      o[t * NS] = f2bf(hr);
    }
    F[(size_t)blk * 256 + n]       = hr;
    F[(size_t)blk * 256 + 128 + n] = hi;
  }
}

// ---------------------------------------------------------------------------
// gemm2s (512 threads / 8 waves): glds-load Hs tile (inverse-swizzled src);
// per-block carry fold from F (R11-identical arithmetic order); apply
// Re correction in-LDS; GEMM2 y[64 x 1024] = Hl * Cb^T with nt stores.
// ---------------------------------------------------------------------------
__global__ __launch_bounds__(512, 4) void gemm2s(const unsigned short* __restrict__ Hs,
                                                 const float* __restrict__ F,
                                                 const float* __restrict__ Ar,
                                                 const float* __restrict__ Ai,
                                                 const unsigned short* __restrict__ Cb,
                                                 float* __restrict__ y) {
  __shared__ __align__(16) char Hl[64 * 256];   // 16 KB swizzled Re(h)
  const int tid  = threadIdx.x;
  const int lane = tid & 63;
  const int wave = tid >> 6;          // 0..7
  const int blk  = blockIdx.x;
  const int c    = blk & 31;
  const size_t m0 = (size_t)blk * CHUNK;

  // stage: wave w rows [w*8, +8), 2 glds (4 rows / 1 KB each)
  const char* tile = (const char*)Hs + (size_t)blk * (CHUNK * NS * 2);
#pragma unroll
  for (int g = 0; g < 2; ++g) {
    const int r0 = wave * 8 + g * 4;
    const int r  = r0 + (lane >> 4);
    const int srcOff = r * 256 + ((((lane & 15)) * 16) ^ ((r & 7) << 4));
    __builtin_amdgcn_global_load_lds(AS1(tile + srcOff), AS3(Hl + r0 * 256), 16, 0, 0);
  }
  __syncthreads();

  // carry fold + in-LDS correction (threads 0..127, R11-identical order)
  if (c != 0 && tid < 128) {
    const int n = tid;
    float ar, ai; adisc(Ar[n], Ai[n], ar, ai);
    float alr = ar, ali = ai;                 // a^CHUNK (2^6)
#pragma unroll
    for (int s = 0; s < 6; ++s) {
      const float tr = alr * alr - ali * ali;
      const float ti = 2.f * alr * ali;
      alr = tr; ali = ti;
    }
    float cr = 0.f, ci = 0.f;                 // carry = h at end of chunk c-1
    const float* Fb = F + (size_t)(blk - c) * 256;
    for (int cc = 0; cc < c; ++cc) {
      const float fr = Fb[(size_t)cc * 256 + n];
      const float fi = Fb[(size_t)cc * 256 + 128 + n];
      const float xr = fmaf(alr, cr, fmaf(-ali, ci, fr));
      const float xi = fmaf(alr, ci, fmaf(ali, cr, fi));
      cr = xr; ci = xi;
    }
    float gr = ar * cr - ai * ci;             // g_t = a^{t+1} * carry
    float gi = ar * ci + ai * cr;
#pragma unroll 8
    for (int t = 0; t < CHUNK; ++t) {
      unsigned short* pp = (unsigned short*)(Hl + t * 256 + ((n * 2) ^ ((t & 7) << 4)));
      *pp = f2bf(bf2f(*pp) + gr);
      const float xr = ar * gr - ai * gi;
      const float xi = ar * gi + ai * gr;
      gr = xr; gi = xi;
    }
  }
  __syncthreads();

  const f32x4 zero = {0.f, 0.f, 0.f, 0.f};
#pragma unroll
  for (int cg = 0; cg < 4; ++cg) {
    const int d0 = (cg * 8 + wave) * 32;
    f32x4 oacc[4][2];
#pragma unroll
    for (int i = 0; i < 4; ++i)
#pragma unroll
      for (int j = 0; j < 2; ++j) oacc[i][j] = zero;

#pragma unroll
    for (int ks = 0; ks < 4; ++ks) {
      bf16x8 af[4], bfr[2];
#pragma unroll
      for (int i = 0; i < 4; ++i) {
        const int r = i * 16 + (lane & 15);
        af[i] = *(const bf16x8*)(Hl + r * 256 + ((ks * 64 + (lane >> 4) * 16) ^ ((r & 7) << 4)));
      }
#pragma unroll
      for (int j = 0; j < 2; ++j)
        bfr[j] = *(const bf16x8*)(Cb + (size_t)(d0 + j * 16 + (lane & 15)) * NS + ks * 32 + (lane >> 4) * 8);
#pragma unroll
      for (int i = 0; i < 4; ++i)
#pragma unroll
        for (int j = 0; j < 2; ++j)
          oacc[i][j] = __builtin_amdgcn_mfma_f32_16x16x32_bf16(af[i], bfr[j], oacc[i][j], 0, 0, 0);
    }
#pragma unroll
    for (int i = 0; i < 4; ++i) {
      const size_t r0 = m0 + i * 16 + (lane >> 4) * 4;
#pragma unroll
      for (int j = 0; j < 2; ++j) {
        const int d = d0 + j * 16 + (lane & 15);
#pragma unroll
        for (int q = 0; q < 4; ++q)
          __builtin_nontemporal_store(oacc[i][j][q], &y[(r0 + q) * DD + d]);
      }
    }
  }
}

// ---------------------------------------------------------------------------
extern "C" void kernel_launch(void* const* d_in, const int* in_sizes, int n_in,
                              void* d_out, int out_size, void* d_ws, size_t ws_size,
                              hipStream_t stream) {
  const float* u  = (const float*)d_in[0];
  const float* Ar = (const float*)d_in[1];
  const float* Ai = (const float*)d_in[2];
  const float* B  = (const float*)d_in[3];
  const float* C  = (const float*)d_in[4];
  float* y = (float*)d_out;
  char* ws = (char*)d_ws;

  unsigned short* Bb = (unsigned short*)(ws);                  // 256 KB (raw B bf16)
  unsigned short* Cb = (unsigned short*)(ws + (256 << 10));    // 256 KB (C bf16)
  float*          F  = (float*)(ws + (512 << 10));             // 512 KB (chunk finals f32)
  unsigned short* Hs = (unsigned short*)(ws + (1024 << 10));   // 8 MB   (Re(h_local) bf16)

  prep_all<<<dim3(1024), dim3(256), 0, stream>>>(B, C, Bb, Cb);
  gemm1s<<<dim3(NB * NCH), dim3(512), 0, stream>>>(u, Ar, Ai, Bb, Hs, F);
  gemm2s<<<dim3(NB * NCH), dim3(512), 0, stream>>>(Hs, F, Ar, Ai, Cb, y);
}

// Round 16
// 74.007 us; speedup vs baseline: 1.3631x; 1.3631x over previous
//
#include <hip/hip_runtime.h>
#include <hip/hip_bf16.h>
#include <cstdint>

#define DT_F    0.01f
#define NB      16      // batch
#define T_SEQ   2048    // sequence
#define DD      1024    // d_in
#define NS      128     // n_state
#define CHUNK   64      // rows per chunk / scan length
#define NCH     32      // chunks per batch

using f32x4  = __attribute__((ext_vector_type(4))) float;
using bf16x8 = __attribute__((ext_vector_type(8))) short;
using fl4    = __attribute__((ext_vector_type(4))) float;

#define AS1(p) ((const __attribute__((address_space(1))) void*)(p))
#define AS3(p) ((__attribute__((address_space(3))) void*)(p))

__device__ __forceinline__ unsigned short f2bf(float f) {
  union { float f; unsigned u; } v; v.f = f;
  unsigned r = v.u + 0x7fffu + ((v.u >> 16) & 1u);   // RNE
  return (unsigned short)(r >> 16);
}
__device__ __forceinline__ float bf2f(unsigned short s) {
  union { unsigned u; float f; } v; v.u = ((unsigned)s) << 16;
  return v.f;
}
__device__ __forceinline__ unsigned short f2bf_hw(float f) {
  __hip_bfloat16 h = __float2bfloat16(f);
  return __builtin_bit_cast(unsigned short, h);
}

// a_disc and the B_disc row-scale c = sqrt(dt)/denom, from raw A (per n)
__device__ __forceinline__ void adisc_full(float Arn, float Ain,
                                           float& ar, float& ai,
                                           float& cr, float& ci) {
  const float dr = 1.f - 0.5f * DT_F * Arn;
  const float di = -0.5f * DT_F * Ain;
  const float inv = 1.f / (dr * dr + di * di);
  const float nr = 1.f + 0.5f * DT_F * Arn;
  const float nim = 0.5f * DT_F * Ain;
  ar = (nr * dr + nim * di) * inv;        // Re(a_disc)
  ai = (nim * dr - nr * di) * inv;        // Im(a_disc)
  const float s = sqrtf(DT_F);
  cr = s * dr * inv;                       // Re(sqrt(dt)/denom)
  ci = -s * di * inv;                      // Im(sqrt(dt)/denom)
}
__device__ __forceinline__ void adisc(float Arn, float Ain, float& ar, float& ai) {
  float cr, ci; adisc_full(Arn, Ain, ar, ai, cr, ci);
}

// ---------------------------------------------------------------------------
// prep_all: blocks 0..511 convert C->bf16; blocks 512..1023 convert B->bf16.
// ---------------------------------------------------------------------------
__global__ void prep_all(const float* __restrict__ B, const float* __restrict__ C,
                         unsigned short* __restrict__ Bb, unsigned short* __restrict__ Cb) {
  const int blk = blockIdx.x;
  const int tid = threadIdx.x;
  if (blk < 512) {
    const int i = blk * 256 + tid;
    Cb[i] = f2bf(C[i]);
  } else {
    const int i = (blk - 512) * 256 + tid;
    Bb[i] = f2bf(B[i]);
  }
}

// ---------------------------------------------------------------------------
// gemm1s (512 threads / 8 waves, R14 form): s_tile[64 x 128] = cvt(u) * Bb^T,
// BK=64, swizzled As/Bs (byte(r,kb) = r*128 + (kb ^ ((r&7)<<4))).
// Epilogue -> swizzled Bt; 128-thread local scan; Re(h)->Hs, finals->F.
// ---------------------------------------------------------------------------
__global__ __launch_bounds__(512, 4) void gemm1s(const float* __restrict__ U,
                                                 const float* __restrict__ Ar,
                                                 const float* __restrict__ Ai,
                                                 const unsigned short* __restrict__ Bb,
                                                 unsigned short* __restrict__ Hs,
                                                 float* __restrict__ F) {
  __shared__ __align__(16) char smem[24576];
  char* As = smem;             // [64] rows x 128 B, swizzled   8 KB
  char* Bs = smem + 8192;      // [128] rows x 128 B, swizzled 16 KB
  char* Bt = smem;             // epilogue: 64 rows x 256 B swizzled

  const int tid  = threadIdx.x;
  const int lane = tid & 63;
  const int wave = tid >> 6;          // 0..7
  const int blk  = blockIdx.x;
  const size_t m0 = (size_t)blk * CHUNK;

  f32x4 acc[4];
  const f32x4 zero = {0.f, 0.f, 0.f, 0.f};
#pragma unroll
  for (int i = 0; i < 4; ++i) acc[i] = zero;

  const int srow = tid >> 3;            // 0..63
  const int scol = (tid & 7) * 8;       // elements 0..56
  const int sb   = srow * 128 + (((tid & 7) * 16) ^ ((srow & 7) << 4));
  const int growl = lane >> 3;          // 0..7
  const int gcolsw = 8 * ((lane & 7) ^ (lane >> 3));   // pre-swizzled source

  for (int k0 = 0; k0 < DD; k0 += 64) {
    __syncthreads();
    // B stage: wave w rows [w*16, +16), 2 glds (8 rows / 1 KB each)
#pragma unroll
    for (int g = 0; g < 2; ++g) {
      const int row = wave * 16 + g * 8;
      const unsigned short* gb = Bb + (size_t)(row + growl) * DD + k0 + gcolsw;
      __builtin_amdgcn_global_load_lds(AS1(gb), AS3(Bs + row * 128), 16, 0, 0);
    }
    // A stage: 64x64 f32 -> bf16, 8 f32/thread, swizzled store
    {
      const float* ga = U + (m0 + srow) * DD + k0 + scol;
      fl4 v0 = *(const fl4*)ga;
      fl4 v1 = *(const fl4*)(ga + 4);
      bf16x8 p0;
#pragma unroll
      for (int e = 0; e < 4; ++e) {
        p0[e] = (short)f2bf_hw(v0[e]); p0[4 + e] = (short)f2bf_hw(v1[e]);
      }
      *(bf16x8*)(As + sb) = p0;
    }
    __syncthreads();
#pragma unroll
    for (int ks = 0; ks < 2; ++ks) {
      const int colb = ks * 64 + (lane >> 4) * 16;   // byte within row
      bf16x8 af[4], bfr;
#pragma unroll
      for (int i = 0; i < 4; ++i) {
        const int r = i * 16 + (lane & 15);
        af[i] = *(const bf16x8*)(As + r * 128 + (colb ^ ((r & 7) << 4)));
      }
      {
        const int r = wave * 16 + (lane & 15);
        bfr = *(const bf16x8*)(Bs + r * 128 + (colb ^ ((r & 7) << 4)));
      }
#pragma unroll
      for (int i = 0; i < 4; ++i)
        acc[i] = __builtin_amdgcn_mfma_f32_16x16x32_bf16(af[i], bfr, acc[i], 0, 0, 0);
    }
  }
  __syncthreads();   // MFMA LDS reads done before Bt overwrites As/Bs

  // epilogue: acc -> swizzled Bt. byte(t, n) = t*256 + ((n*2) ^ ((t&7)<<4))
#pragma unroll
  for (int i = 0; i < 4; ++i) {
    const int n = wave * 16 + (lane & 15);
#pragma unroll
    for (int q = 0; q < 4; ++q) {
      const int t = i * 16 + (lane >> 4) * 4 + q;
      *(unsigned short*)(Bt + t * 256 + ((n * 2) ^ ((t & 7) << 4))) = f2bf_hw(acc[i][q]);
    }
  }
  __syncthreads();

  // local scan (threads 0..127): br = cr*s, bi = ci*s; Re(h)->Hs; finals->F
  if (tid < 128) {
    const int n = tid;
    float ar, ai, cr, ci; adisc_full(Ar[n], Ai[n], ar, ai, cr, ci);
    float hr = 0.f, hi = 0.f;
    unsigned short* o = Hs + (size_t)blk * (CHUNK * NS) + n;
#pragma unroll 8
    for (int t = 0; t < CHUNK; ++t) {
      const float s = bf2f(*(const unsigned short*)(Bt + t * 256 + ((n * 2) ^ ((t & 7) << 4))));
      const float br = cr * s;
      const float bi = ci * s;
      const float xr = fmaf(ar, hr, fmaf(-ai, hi, br));
      const float xi = fmaf(ar, hi, fmaf(ai, hr, bi));
      hr = xr; hi = xi;
      o[t * NS] = f2bf(hr);
    }
    F[(size_t)blk * 256 + n]       = hr;
    F[(size_t)blk * 256 + 128 + n] = hi;
  }
}

// ---------------------------------------------------------------------------
// gemm2s (512 threads / 8 waves): glds-load Hs tile (inverse-swizzled src);
// per-block carry fold from F (R11-identical arithmetic order); apply
// Re correction in-LDS; GEMM2 y[64 x 1024] = Hl * Cb^T.
// ---------------------------------------------------------------------------
__global__ __launch_bounds__(512, 4) void gemm2s(const unsigned short* __restrict__ Hs,
                                                 const float* __restrict__ F,
                                                 const float* __restrict__ Ar,
                                                 const float* __restrict__ Ai,
                                                 const unsigned short* __restrict__ Cb,
                                                 float* __restrict__ y) {
  __shared__ __align__(16) char Hl[64 * 256];   // 16 KB swizzled Re(h)
  const int tid  = threadIdx.x;
  const int lane = tid & 63;
  const int wave = tid >> 6;          // 0..7
  const int blk  = blockIdx.x;
  const int c    = blk & 31;
  const size_t m0 = (size_t)blk * CHUNK;

  // stage: wave w rows [w*8, +8), 2 glds (4 rows / 1 KB each)
  const char* tile = (const char*)Hs + (size_t)blk * (CHUNK * NS * 2);
#pragma unroll
  for (int g = 0; g < 2; ++g) {
    const int r0 = wave * 8 + g * 4;
    const int r  = r0 + (lane >> 4);
    const int srcOff = r * 256 + ((((lane & 15)) * 16) ^ ((r & 7) << 4));
    __builtin_amdgcn_global_load_lds(AS1(tile + srcOff), AS3(Hl + r0 * 256), 16, 0, 0);
  }
  __syncthreads();

  // carry fold + in-LDS correction (threads 0..127, R11-identical order)
  if (c != 0 && tid < 128) {
    const int n = tid;
    float ar, ai; adisc(Ar[n], Ai[n], ar, ai);
    float alr = ar, ali = ai;                 // a^CHUNK (2^6)
#pragma unroll
    for (int s = 0; s < 6; ++s) {
      const float tr = alr * alr - ali * ali;
      const float ti = 2.f * alr * ali;
      alr = tr; ali = ti;
    }
    float cr = 0.f, ci = 0.f;                 // carry = h at end of chunk c-1
    const float* Fb = F + (size_t)(blk - c) * 256;
    for (int cc = 0; cc < c; ++cc) {
      const float fr = Fb[(size_t)cc * 256 + n];
      const float fi = Fb[(size_t)cc * 256 + 128 + n];
      const float xr = fmaf(alr, cr, fmaf(-ali, ci, fr));
      const float xi = fmaf(alr, ci, fmaf(ali, cr, fi));
      cr = xr; ci = xi;
    }
    float gr = ar * cr - ai * ci;             // g_t = a^{t+1} * carry
    float gi = ar * ci + ai * cr;
#pragma unroll 8
    for (int t = 0; t < CHUNK; ++t) {
      unsigned short* pp = (unsigned short*)(Hl + t * 256 + ((n * 2) ^ ((t & 7) << 4)));
      *pp = f2bf(bf2f(*pp) + gr);
      const float xr = ar * gr - ai * gi;
      const float xi = ar * gi + ai * gr;
      gr = xr; gi = xi;
    }
  }
  __syncthreads();

  const f32x4 zero = {0.f, 0.f, 0.f, 0.f};
#pragma unroll
  for (int cg = 0; cg < 4; ++cg) {
    const int d0 = (cg * 8 + wave) * 32;
    f32x4 oacc[4][2];
#pragma unroll
    for (int i = 0; i < 4; ++i)
#pragma unroll
      for (int j = 0; j < 2; ++j) oacc[i][j] = zero;

#pragma unroll
    for (int ks = 0; ks < 4; ++ks) {
      bf16x8 af[4], bfr[2];
#pragma unroll
      for (int i = 0; i < 4; ++i) {
        const int r = i * 16 + (lane & 15);
        af[i] = *(const bf16x8*)(Hl + r * 256 + ((ks * 64 + (lane >> 4) * 16) ^ ((r & 7) << 4)));
      }
#pragma unroll
      for (int j = 0; j < 2; ++j)
        bfr[j] = *(const bf16x8*)(Cb + (size_t)(d0 + j * 16 + (lane & 15)) * NS + ks * 32 + (lane >> 4) * 8);
#pragma unroll
      for (int i = 0; i < 4; ++i)
#pragma unroll
        for (int j = 0; j < 2; ++j)
          oacc[i][j] = __builtin_amdgcn_mfma_f32_16x16x32_bf16(af[i], bfr[j], oacc[i][j], 0, 0, 0);
    }
#pragma unroll
    for (int i = 0; i < 4; ++i) {
      const size_t r0 = m0 + i * 16 + (lane >> 4) * 4;
#pragma unroll
      for (int j = 0; j < 2; ++j) {
        const int d = d0 + j * 16 + (lane & 15);
#pragma unroll
        for (int q = 0; q < 4; ++q)
          y[(r0 + q) * DD + d] = oacc[i][j][q];
      }
    }
  }
}

// ---------------------------------------------------------------------------
extern "C" void kernel_launch(void* const* d_in, const int* in_sizes, int n_in,
                              void* d_out, int out_size, void* d_ws, size_t ws_size,
                              hipStream_t stream) {
  const float* u  = (const float*)d_in[0];
  const float* Ar = (const float*)d_in[1];
  const float* Ai = (const float*)d_in[2];
  const float* B  = (const float*)d_in[3];
  const float* C  = (const float*)d_in[4];
  float* y = (float*)d_out;
  char* ws = (char*)d_ws;

  unsigned short* Bb = (unsigned short*)(ws);                  // 256 KB (raw B bf16)
  unsigned short* Cb = (unsigned short*)(ws + (256 << 10));    // 256 KB (C bf16)
  float*          F  = (float*)(ws + (512 << 10));             // 512 KB (chunk finals f32)
  unsigned short* Hs = (unsigned short*)(ws + (1024 << 10));   // 8 MB   (Re(h_local) bf16)

  prep_all<<<dim3(1024), dim3(256), 0, stream>>>(B, C, Bb, Cb);
  gemm1s<<<dim3(NB * NCH), dim3(512), 0, stream>>>(u, Ar, Ai, Bb, Hs, F);
  gemm2s<<<dim3(NB * NCH), dim3(512), 0, stream>>>(Hs, F, Ar, Ai, Cb, y);
}

// Round 17
// 72.613 us; speedup vs baseline: 1.3893x; 1.0192x over previous
//
#include <hip/hip_runtime.h>
#include <hip/hip_bf16.h>
#include <cstdint>

#define DT_F    0.01f
#define NB      16      // batch
#define T_SEQ   2048    // sequence
#define DD      1024    // d_in
#define NS      128     // n_state
#define CHUNK   64      // rows per chunk / scan length
#define NCH     32      // chunks per batch

using f32x4  = __attribute__((ext_vector_type(4))) float;
using bf16x8 = __attribute__((ext_vector_type(8))) short;
using fl4    = __attribute__((ext_vector_type(4))) float;

#define AS1(p) ((const __attribute__((address_space(1))) void*)(p))
#define AS3(p) ((__attribute__((address_space(3))) void*)(p))

__device__ __forceinline__ unsigned short f2bf(float f) {
  union { float f; unsigned u; } v; v.f = f;
  unsigned r = v.u + 0x7fffu + ((v.u >> 16) & 1u);   // RNE
  return (unsigned short)(r >> 16);
}
__device__ __forceinline__ float bf2f(unsigned short s) {
  union { unsigned u; float f; } v; v.u = ((unsigned)s) << 16;
  return v.f;
}
__device__ __forceinline__ unsigned short f2bf_hw(float f) {
  __hip_bfloat16 h = __float2bfloat16(f);
  return __builtin_bit_cast(unsigned short, h);
}

// a_disc and the B_disc row-scale c = sqrt(dt)/denom, from raw A (per n)
__device__ __forceinline__ void adisc_full(float Arn, float Ain,
                                           float& ar, float& ai,
                                           float& cr, float& ci) {
  const float dr = 1.f - 0.5f * DT_F * Arn;
  const float di = -0.5f * DT_F * Ain;
  const float inv = 1.f / (dr * dr + di * di);
  const float nr = 1.f + 0.5f * DT_F * Arn;
  const float nim = 0.5f * DT_F * Ain;
  ar = (nr * dr + nim * di) * inv;        // Re(a_disc)
  ai = (nim * dr - nr * di) * inv;        // Im(a_disc)
  const float s = sqrtf(DT_F);
  cr = s * dr * inv;                       // Re(sqrt(dt)/denom)
  ci = -s * di * inv;                      // Im(sqrt(dt)/denom)
}
__device__ __forceinline__ void adisc(float Arn, float Ain, float& ar, float& ai) {
  float cr, ci; adisc_full(Arn, Ain, ar, ai, cr, ci);
}

// ---------------------------------------------------------------------------
// prep_all: blocks 0..511 convert C->bf16; blocks 512..1023 convert B->bf16.
// ---------------------------------------------------------------------------
__global__ void prep_all(const float* __restrict__ B, const float* __restrict__ C,
                         unsigned short* __restrict__ Bb, unsigned short* __restrict__ Cb) {
  const int blk = blockIdx.x;
  const int tid = threadIdx.x;
  if (blk < 512) {
    const int i = blk * 256 + tid;
    Cb[i] = f2bf(C[i]);
  } else {
    const int i = (blk - 512) * 256 + tid;
    Bb[i] = f2bf(B[i]);
  }
}

// ---------------------------------------------------------------------------
// gemm1s (512 threads / 8 waves): s_tile[64 x 128] = cvt(u) * Bb^T, BK=64.
// Wave w owns N-cols [w*16, +16) -> acc[4]. Swizzled As/Bs layout
// (byte(r,kb) = r*128 + (kb ^ ((r&7)<<4))); A-stage 8 f32/thread.
// Epilogue -> swizzled Bt; 128-thread local scan; Re(h)->Hs, finals->F.
// ---------------------------------------------------------------------------
__global__ __launch_bounds__(512, 4) void gemm1s(const float* __restrict__ U,
                                                 const float* __restrict__ Ar,
                                                 const float* __restrict__ Ai,
                                                 const unsigned short* __restrict__ Bb,
                                                 unsigned short* __restrict__ Hs,
                                                 float* __restrict__ F) {
  __shared__ __align__(16) char smem[24576];
  char* As = smem;             // [64] rows x 128 B, swizzled   8 KB
  char* Bs = smem + 8192;      // [128] rows x 128 B, swizzled 16 KB
  char* Bt = smem;             // epilogue: 64 rows x 256 B swizzled

  const int tid  = threadIdx.x;
  const int lane = tid & 63;
  const int wave = tid >> 6;          // 0..7
  const int blk  = blockIdx.x;
  const size_t m0 = (size_t)blk * CHUNK;

  f32x4 acc[4];
  const f32x4 zero = {0.f, 0.f, 0.f, 0.f};
#pragma unroll
  for (int i = 0; i < 4; ++i) acc[i] = zero;

  const int srow = tid >> 3;            // 0..63
  const int scol = (tid & 7) * 8;       // elements 0..56
  const int sb   = srow * 128 + (((tid & 7) * 16) ^ ((srow & 7) << 4));
  const int growl = lane >> 3;          // 0..7
  const int gcolsw = 8 * ((lane & 7) ^ (lane >> 3));   // pre-swizzled source

  for (int k0 = 0; k0 < DD; k0 += 64) {
    __syncthreads();
    // B stage: wave w rows [w*16, +16), 2 glds (8 rows / 1 KB each)
#pragma unroll
    for (int g = 0; g < 2; ++g) {
      const int row = wave * 16 + g * 8;
      const unsigned short* gb = Bb + (size_t)(row + growl) * DD + k0 + gcolsw;
      __builtin_amdgcn_global_load_lds(AS1(gb), AS3(Bs + row * 128), 16, 0, 0);
    }
    // A stage: 64x64 f32 -> bf16, 8 f32/thread, swizzled store
    {
      const float* ga = U + (m0 + srow) * DD + k0 + scol;
      fl4 v0 = *(const fl4*)ga;
      fl4 v1 = *(const fl4*)(ga + 4);
      bf16x8 p0;
#pragma unroll
      for (int e = 0; e < 4; ++e) {
        p0[e] = (short)f2bf_hw(v0[e]); p0[4 + e] = (short)f2bf_hw(v1[e]);
      }
      *(bf16x8*)(As + sb) = p0;
    }
    __syncthreads();
#pragma unroll
    for (int ks = 0; ks < 2; ++ks) {
      const int colb = ks * 64 + (lane >> 4) * 16;   // byte within row
      bf16x8 af[4], bfr;
#pragma unroll
      for (int i = 0; i < 4; ++i) {
        const int r = i * 16 + (lane & 15);
        af[i] = *(const bf16x8*)(As + r * 128 + (colb ^ ((r & 7) << 4)));
      }
      {
        const int r = wave * 16 + (lane & 15);
        bfr = *(const bf16x8*)(Bs + r * 128 + (colb ^ ((r & 7) << 4)));
      }
#pragma unroll
      for (int i = 0; i < 4; ++i)
        acc[i] = __builtin_amdgcn_mfma_f32_16x16x32_bf16(af[i], bfr, acc[i], 0, 0, 0);
    }
  }
  __syncthreads();   // MFMA LDS reads done before Bt overwrites As/Bs

  // epilogue: acc -> swizzled Bt. byte(t, n) = t*256 + ((n*2) ^ ((t&7)<<4))
#pragma unroll
  for (int i = 0; i < 4; ++i) {
    const int n = wave * 16 + (lane & 15);
#pragma unroll
    for (int q = 0; q < 4; ++q) {
      const int t = i * 16 + (lane >> 4) * 4 + q;
      *(unsigned short*)(Bt + t * 256 + ((n * 2) ^ ((t & 7) << 4))) = f2bf_hw(acc[i][q]);
    }
  }
  __syncthreads();

  // local scan (threads 0..127): br = cr*s, bi = ci*s; Re(h)->Hs; finals->F
  if (tid < 128) {
    const int n = tid;
    float ar, ai, cr, ci; adisc_full(Ar[n], Ai[n], ar, ai, cr, ci);
    float hr = 0.f, hi = 0.f;
    unsigned short* o = Hs + (size_t)blk * (CHUNK * NS) + n;
#pragma unroll 8
    for (int t = 0; t < CHUNK; ++t) {
      const float s = bf2f(*(const unsigned short*)(Bt + t * 256 + ((n * 2) ^ ((t & 7) << 4))));
      const float br = cr * s;
      const float bi = ci * s;
      const float xr = fmaf(ar, hr, fmaf(-ai, hi, br));
      const float xi = fmaf(ar, hi, fmaf(ai, hr, bi));
      hr = xr; hi = xi;
      o[t * NS] = f2bf(hr);
    }
    F[(size_t)blk * 256 + n]       = hr;
    F[(size_t)blk * 256 + 128 + n] = hi;
  }
}

// ---------------------------------------------------------------------------
// carry_scan (LDS-bulk): one block per batch b, 256 threads. Cooperatively
// stage F[b] (32 KB) into LDS, then threads 0..127 fold the 32 chunk finals
// (identical arithmetic order) and store g0 = a_disc * carry[c].
// ---------------------------------------------------------------------------
__global__ void carry_scan(const float* __restrict__ F,
                           const float* __restrict__ Ar, const float* __restrict__ Ai,
                           float* __restrict__ G) {
  __shared__ float Fl[NCH * 256];   // 32 KB
  const int b = blockIdx.x;
  const int tid = threadIdx.x;
  const float4* src = (const float4*)(F + (size_t)b * NCH * 256);
  float4* dst = (float4*)Fl;
#pragma unroll
  for (int i = 0; i < NCH * 64 / 256; ++i)
    dst[tid + i * 256] = src[tid + i * 256];
  __syncthreads();
  if (tid < 128) {
    const int n = tid;
    float ar, ai; adisc(Ar[n], Ai[n], ar, ai);
    float alr = ar, ali = ai;                 // a^CHUNK (2^6)
#pragma unroll
    for (int s = 0; s < 6; ++s) {
      const float tr = alr * alr - ali * ali;
      const float ti = 2.f * alr * ali;
      alr = tr; ali = ti;
    }
    float cr = 0.f, ci = 0.f;                 // carry at start of chunk 0
    for (int c = 0; c < NCH; ++c) {
      const size_t idx = ((size_t)b * NCH + c) * 256 + n;
      G[idx]       = ar * cr - ai * ci;       // g0 = a * carry[c]
      G[idx + 128] = ar * ci + ai * cr;
      const float fr = Fl[c * 256 + n];
      const float fi = Fl[c * 256 + 128 + n];
      const float xr = fmaf(alr, cr, fmaf(-ali, ci, fr));
      const float xi = fmaf(alr, ci, fmaf(ali, cr, fi));
      cr = xr; ci = xi;                       // carry at start of chunk c+1
    }
  }
}

// ---------------------------------------------------------------------------
// gemm2s (512 threads / 8 waves): glds-load Hs tile (inverse-swizzled src);
// apply pre-seeded g correction in-LDS; GEMM2 y[64 x 1024] = Hl * Cb^T.
// Wave w covers d-cols (cg*8+w)*32 .. +32 per cg (cg 0..3) -> oacc[4][2].
// ---------------------------------------------------------------------------
__global__ __launch_bounds__(512, 4) void gemm2s(const unsigned short* __restrict__ Hs,
                                                 const float* __restrict__ G,
                                                 const float* __restrict__ Ar,
                                                 const float* __restrict__ Ai,
                                                 const unsigned short* __restrict__ Cb,
                                                 float* __restrict__ y) {
  __shared__ __align__(16) char Hl[64 * 256];   // 16 KB swizzled Re(h)
  const int tid  = threadIdx.x;
  const int lane = tid & 63;
  const int wave = tid >> 6;          // 0..7
  const int blk  = blockIdx.x;
  const int c    = blk & 31;
  const size_t m0 = (size_t)blk * CHUNK;

  // stage: wave w rows [w*8, +8), 2 glds (4 rows / 1 KB each)
  const char* tile = (const char*)Hs + (size_t)blk * (CHUNK * NS * 2);
#pragma unroll
  for (int g = 0; g < 2; ++g) {
    const int r0 = wave * 8 + g * 4;
    const int r  = r0 + (lane >> 4);
    const int srcOff = r * 256 + ((((lane & 15)) * 16) ^ ((r & 7) << 4));
    __builtin_amdgcn_global_load_lds(AS1(tile + srcOff), AS3(Hl + r0 * 256), 16, 0, 0);
  }
  __syncthreads();

  // correction (threads 0..127): g from carry_scan, advance by a per step
  if (c != 0 && tid < 128) {
    const int n = tid;
    float ar, ai; adisc(Ar[n], Ai[n], ar, ai);
    float gr = G[(size_t)blk * 256 + n];
    float gi = G[(size_t)blk * 256 + 128 + n];
#pragma unroll 8
    for (int t = 0; t < CHUNK; ++t) {
      unsigned short* pp = (unsigned short*)(Hl + t * 256 + ((n * 2) ^ ((t & 7) << 4)));
      *pp = f2bf(bf2f(*pp) + gr);
      const float xr = ar * gr - ai * gi;
      const float xi = ar * gi + ai * gr;
      gr = xr; gi = xi;
    }
  }
  __syncthreads();

  const f32x4 zero = {0.f, 0.f, 0.f, 0.f};
#pragma unroll
  for (int cg = 0; cg < 4; ++cg) {
    const int d0 = (cg * 8 + wave) * 32;
    f32x4 oacc[4][2];
#pragma unroll
    for (int i = 0; i < 4; ++i)
#pragma unroll
      for (int j = 0; j < 2; ++j) oacc[i][j] = zero;

#pragma unroll
    for (int ks = 0; ks < 4; ++ks) {
      bf16x8 af[4], bfr[2];
#pragma unroll
      for (int i = 0; i < 4; ++i) {
        const int r = i * 16 + (lane & 15);
        af[i] = *(const bf16x8*)(Hl + r * 256 + ((ks * 64 + (lane >> 4) * 16) ^ ((r & 7) << 4)));
      }
#pragma unroll
      for (int j = 0; j < 2; ++j)
        bfr[j] = *(const bf16x8*)(Cb + (size_t)(d0 + j * 16 + (lane & 15)) * NS + ks * 32 + (lane >> 4) * 8);
#pragma unroll
      for (int i = 0; i < 4; ++i)
#pragma unroll
        for (int j = 0; j < 2; ++j)
          oacc[i][j] = __builtin_amdgcn_mfma_f32_16x16x32_bf16(af[i], bfr[j], oacc[i][j], 0, 0, 0);
    }
#pragma unroll
    for (int i = 0; i < 4; ++i) {
      const size_t r0 = m0 + i * 16 + (lane >> 4) * 4;
#pragma unroll
      for (int j = 0; j < 2; ++j) {
        const int d = d0 + j * 16 + (lane & 15);
#pragma unroll
        for (int q = 0; q < 4; ++q)
          y[(r0 + q) * DD + d] = oacc[i][j][q];
      }
    }
  }
}

// ---------------------------------------------------------------------------
extern "C" void kernel_launch(void* const* d_in, const int* in_sizes, int n_in,
                              void* d_out, int out_size, void* d_ws, size_t ws_size,
                              hipStream_t stream) {
  const float* u  = (const float*)d_in[0];
  const float* Ar = (const float*)d_in[1];
  const float* Ai = (const float*)d_in[2];
  const float* B  = (const float*)d_in[3];
  const float* C  = (const float*)d_in[4];
  float* y = (float*)d_out;
  char* ws = (char*)d_ws;

  unsigned short* Bb = (unsigned short*)(ws);                  // 256 KB (raw B bf16)
  unsigned short* Cb = (unsigned short*)(ws + (256 << 10));    // 256 KB (C bf16)
  float*          F  = (float*)(ws + (512 << 10));             // 512 KB (chunk finals f32)
  float*          G  = (float*)(ws + (1024 << 10));            // 512 KB (seeded carries f32)
  unsigned short* Hs = (unsigned short*)(ws + (1536 << 10));   // 8 MB   (Re(h_local) bf16)

  prep_all<<<dim3(1024), dim3(256), 0, stream>>>(B, C, Bb, Cb);
  gemm1s<<<dim3(NB * NCH), dim3(512), 0, stream>>>(u, Ar, Ai, Bb, Hs, F);
  carry_scan<<<dim3(NB), dim3(256), 0, stream>>>(F, Ar, Ai, G);
  gemm2s<<<dim3(NB * NCH), dim3(512), 0, stream>>>(Hs, G, Ar, Ai, Cb, y);
}